// Round 1
// baseline (198.639 us; speedup 1.0000x reference)
//
#include <hip/hip_runtime.h>

typedef float f32x4 __attribute__((ext_vector_type(4)));
typedef __bf16 bf16x8 __attribute__((ext_vector_type(8)));

// XOR swizzle in elements (2B): byte ^= ((row&7)<<4)  ->  elem col ^= ((row&7)<<3)
__device__ __forceinline__ int swz(int row, int col) {
  return col ^ ((row & 7) << 3);
}

// load 8 consecutive f32, convert to bf16x8 (RNE via compiler cvt)
__device__ __forceinline__ bf16x8 cvt8(const float* __restrict__ src) {
  f32x4 a = *(const f32x4*)src;
  f32x4 b = *(const f32x4*)(src + 4);
  bf16x8 r;
  r[0] = (__bf16)a[0]; r[1] = (__bf16)a[1]; r[2] = (__bf16)a[2]; r[3] = (__bf16)a[3];
  r[4] = (__bf16)b[0]; r[5] = (__bf16)b[1]; r[6] = (__bf16)b[2]; r[7] = (__bf16)b[3];
  return r;
}

// ---------------------------------------------------------------------------
// Kernel 1: per-node precompute  PQ[n][0:64]  = W1[:, 0:128]   @ x[n]
//                                PQ[n][64:128]= W1[:, 128:256] @ x[n]
// One 256-thread block handles 64 nodes. GEMM [64 x 128] @ [128 x 128].
// ---------------------------------------------------------------------------
__global__ __launch_bounds__(256, 2)
void pq_kernel(const float* __restrict__ x, const float* __restrict__ W1,
               __bf16* __restrict__ pq, int n_nodes)
{
  __shared__ __align__(16) __bf16 xbf[64 * 128];
  __shared__ __align__(16) __bf16 wab[128 * 128];

  const int tid  = threadIdx.x;
  const int lane = tid & 63;
  const int w    = tid >> 6;
  const int base = blockIdx.x * 64;

  // stage B = [n=0..127][k=0..127]; n<64 -> W1[n][k], n>=64 -> W1[n-64][128+k]
  for (int i = tid; i < 128 * 16; i += 256) {
    int row = i >> 4, blk = i & 15;
    const float* src = W1 + (row & 63) * 384 + ((row >> 6) << 7) + blk * 8;
    *(bf16x8*)&wab[row * 128 + swz(row, blk * 8)] = cvt8(src);
  }
  // stage A = x rows (clamped for tail block; results discarded)
  for (int i = tid; i < 64 * 16; i += 256) {
    int row = i >> 4, blk = i & 15;
    int node = base + row; if (node >= n_nodes) node = 0;
    *(bf16x8*)&xbf[row * 128 + swz(row, blk * 8)] = cvt8(x + (size_t)node * 128 + blk * 8);
  }
  __syncthreads();

  const int lrow = lane & 15;
  const int lkb  = (lane >> 4) << 3;   // k sub-block base within 32

  f32x4 acc[8] = {};
#pragma unroll
  for (int kk = 0; kk < 4; ++kk) {
    int k = kk * 32 + lkb;
    int arow = w * 16 + lrow;
    bf16x8 a = *(bf16x8*)&xbf[arow * 128 + swz(arow, k)];
#pragma unroll
    for (int nt = 0; nt < 8; ++nt) {
      int brow = nt * 16 + lrow;
      bf16x8 b = *(bf16x8*)&wab[brow * 128 + swz(brow, k)];
      acc[nt] = __builtin_amdgcn_mfma_f32_16x16x32_bf16(a, b, acc[nt], 0, 0, 0);
    }
  }

  // D layout: col = lane&15, row = (lane>>4)*4 + r
#pragma unroll
  for (int nt = 0; nt < 8; ++nt) {
#pragma unroll
    for (int r = 0; r < 4; ++r) {
      int nrow = base + w * 16 + ((lane >> 4) << 2) + r;
      if (nrow < n_nodes)
        pq[(size_t)nrow * 128 + nt * 16 + lrow] = (__bf16)acc[nt][r];
    }
  }
}

// ---------------------------------------------------------------------------
// Kernel 2: fused edge MLP. Persistent blocks, 64 edges per tile.
//   h1 = relu(e_bf16 @ W1c^T + PQ[src][0:64] + PQ[dst][64:128] + b1)
//   h2 = relu(h1 @ W2^T + b2);  out = h2 . W3 + b3
// ---------------------------------------------------------------------------
__global__ __launch_bounds__(256, 2)
void edge_kernel(const int* __restrict__ ei, const float* __restrict__ e,
                 const __bf16* __restrict__ pq,
                 const float* __restrict__ W1, const float* __restrict__ b1,
                 const float* __restrict__ W2, const float* __restrict__ b2,
                 const float* __restrict__ W3, const float* __restrict__ b3,
                 float* __restrict__ out, int E, int ntiles)
{
  __shared__ __align__(16) __bf16 wc [64 * 128];  // W1c rows [h][k]
  __shared__ __align__(16) __bf16 w2l[64 * 64];   // W2 rows  [h][k]
  __shared__ __align__(16) __bf16 ebf[64 * 128];  // e tile   [edge][k]
  __shared__ __align__(16) __bf16 h1l[64 * 64];   // h1 tile  [edge][h]
  __shared__ float prel[64 * 68];                 // pre-activation bias table (padded stride 68)
  __shared__ float b1l[64], b2l[64], w3l[64];

  const int tid  = threadIdx.x;
  const int lane = tid & 63;
  const int w    = tid >> 6;
  const int lrow = lane & 15;
  const int lkb  = (lane >> 4) << 3;

  // one-time weight staging (persistent block)
  for (int i = tid; i < 64 * 16; i += 256) {
    int row = i >> 4, blk = i & 15;
    *(bf16x8*)&wc[row * 128 + swz(row, blk * 8)] = cvt8(W1 + row * 384 + 256 + blk * 8);
  }
  for (int i = tid; i < 64 * 8; i += 256) {
    int row = i >> 3, blk = i & 7;
    *(bf16x8*)&w2l[row * 64 + swz(row, blk * 8)] = cvt8(W2 + row * 64 + blk * 8);
  }
  if (tid < 64) { b1l[tid] = b1[tid]; b2l[tid] = b2[tid]; w3l[tid] = W3[tid]; }
  const float b3v = b3[0];
  __syncthreads();

  for (int tile = blockIdx.x; tile < ntiles; tile += gridDim.x) {
    const int ebase = tile * 64;

    // stage e tile -> bf16, swizzled
    for (int i = tid; i < 64 * 16; i += 256) {
      int row = i >> 4, blk = i & 15;
      int er = ebase + row; if (er >= E) er = E - 1;
      *(bf16x8*)&ebf[row * 128 + swz(row, blk * 8)] = cvt8(e + (size_t)er * 128 + blk * 8);
    }
    // build pre-activation table: pre[edge][h] = b1[h] + P[src][h] + Q[dst][h]
    {
      int h = tid & 63, grp = tid >> 6;
      float bb = b1l[h];
#pragma unroll
      for (int es = 0; es < 16; ++es) {
        int row  = grp * 16 + es;
        int edge = ebase + row; if (edge >= E) edge = E - 1;
        int s = ei[edge], d = ei[E + edge];
        prel[row * 68 + h] = bb + (float)pq[(size_t)s * 128 + h]
                                + (float)pq[(size_t)d * 128 + 64 + h];
      }
    }
    __syncthreads();

    // layer 1: [64 x 128] @ [128 x 64]
    f32x4 acc1[4] = {};
#pragma unroll
    for (int kk = 0; kk < 4; ++kk) {
      int k = kk * 32 + lkb;
      int arow = w * 16 + lrow;
      bf16x8 a = *(bf16x8*)&ebf[arow * 128 + swz(arow, k)];
#pragma unroll
      for (int nt = 0; nt < 4; ++nt) {
        int brow = nt * 16 + lrow;
        bf16x8 b = *(bf16x8*)&wc[brow * 128 + swz(brow, k)];
        acc1[nt] = __builtin_amdgcn_mfma_f32_16x16x32_bf16(a, b, acc1[nt], 0, 0, 0);
      }
    }
    // epilogue 1: h1 = relu(acc + pre) -> bf16 LDS (wave-local rows; in-order DS)
#pragma unroll
    for (int nt = 0; nt < 4; ++nt) {
#pragma unroll
      for (int r = 0; r < 4; ++r) {
        int row = w * 16 + ((lane >> 4) << 2) + r;
        int h   = nt * 16 + lrow;
        float v = acc1[nt][r] + prel[row * 68 + h];
        v = v > 0.f ? v : 0.f;
        h1l[row * 64 + (h ^ ((row & 7) << 3))] = (__bf16)v;
      }
    }

    // layer 2: [64 x 64] @ [64 x 64]
    f32x4 acc2[4] = {};
#pragma unroll
    for (int ks = 0; ks < 2; ++ks) {
      int k = ks * 32 + lkb;
      int arow = w * 16 + lrow;
      bf16x8 a = *(bf16x8*)&h1l[arow * 64 + swz(arow, k)];
#pragma unroll
      for (int nt = 0; nt < 4; ++nt) {
        int brow = nt * 16 + lrow;
        bf16x8 b = *(bf16x8*)&w2l[brow * 64 + swz(brow, k)];
        acc2[nt] = __builtin_amdgcn_mfma_f32_16x16x32_bf16(a, b, acc2[nt], 0, 0, 0);
      }
    }

    // epilogue 2 + layer 3: per-lane partial dot, reduce across 16 lanes
    float part[4] = {0.f, 0.f, 0.f, 0.f};
#pragma unroll
    for (int nt = 0; nt < 4; ++nt) {
      int h = nt * 16 + lrow;
      float w3v = w3l[h], b2v = b2l[h];
#pragma unroll
      for (int r = 0; r < 4; ++r) {
        float v = acc2[nt][r] + b2v;
        v = v > 0.f ? v : 0.f;
        part[r] += v * w3v;
      }
    }
#pragma unroll
    for (int m = 1; m < 16; m <<= 1) {
#pragma unroll
      for (int r = 0; r < 4; ++r) part[r] += __shfl_xor(part[r], m, 64);
    }
    if (lrow == 0) {
#pragma unroll
      for (int r = 0; r < 4; ++r) {
        int edge = ebase + w * 16 + ((lane >> 4) << 2) + r;
        if (edge < E) out[edge] = part[r] + b3v;
      }
    }
    __syncthreads();  // protect ebf/prel restaging
  }
}

// ---------------------------------------------------------------------------
// Exact f32 fallback (only if ws too small): one 64-thread block per edge.
// ---------------------------------------------------------------------------
__global__ void naive_kernel(const int* __restrict__ ei, const float* __restrict__ x,
                             const float* __restrict__ e,
                             const float* __restrict__ W1, const float* __restrict__ b1,
                             const float* __restrict__ W2, const float* __restrict__ b2,
                             const float* __restrict__ W3, const float* __restrict__ b3,
                             float* __restrict__ out, int E)
{
  __shared__ float h1[64];
  int edge = blockIdx.x;
  int h = threadIdx.x;
  int s = ei[edge], d = ei[E + edge];
  const float* w1r = W1 + h * 384;
  float acc = b1[h];
  for (int k = 0; k < 128; ++k) acc += w1r[k]       * x[(size_t)s * 128 + k];
  for (int k = 0; k < 128; ++k) acc += w1r[128 + k] * x[(size_t)d * 128 + k];
  for (int k = 0; k < 128; ++k) acc += w1r[256 + k] * e[(size_t)edge * 128 + k];
  h1[h] = acc > 0.f ? acc : 0.f;
  __syncthreads();
  float acc2 = b2[h];
  for (int k = 0; k < 64; ++k) acc2 += W2[h * 64 + k] * h1[k];
  acc2 = acc2 > 0.f ? acc2 : 0.f;
  float p = acc2 * W3[h];
  for (int m = 1; m < 64; m <<= 1) p += __shfl_xor(p, m, 64);
  if (h == 0) out[edge] = p + b3[0];
}

extern "C" void kernel_launch(void* const* d_in, const int* in_sizes, int n_in,
                              void* d_out, int out_size, void* d_ws, size_t ws_size,
                              hipStream_t stream) {
  const int*   ei = (const int*)d_in[0];
  const float* x  = (const float*)d_in[1];
  const float* e  = (const float*)d_in[2];
  const float* W1 = (const float*)d_in[3];
  const float* b1 = (const float*)d_in[4];
  const float* W2 = (const float*)d_in[5];
  const float* b2 = (const float*)d_in[6];
  const float* W3 = (const float*)d_in[7];
  const float* b3 = (const float*)d_in[8];
  float* out = (float*)d_out;

  const int E = in_sizes[0] / 2;
  const int N = in_sizes[1] / 128;

  const size_t need = (size_t)N * 128 * sizeof(__bf16);
  if (ws_size < need) {
    naive_kernel<<<E, 64, 0, stream>>>(ei, x, e, W1, b1, W2, b2, W3, b3, out, E);
    return;
  }

  __bf16* pq = (__bf16*)d_ws;
  const int nwg = (N + 63) / 64;
  pq_kernel<<<nwg, 256, 0, stream>>>(x, W1, pq, N);

  const int ntiles = (E + 63) / 64;
  const int grid   = ntiles < 512 ? ntiles : 512;
  edge_kernel<<<grid, 256, 0, stream>>>(ei, e, pq, W1, b1, W2, b2, W3, b3, out, E, ntiles);
}